// Round 8
// baseline (8091.628 us; speedup 1.0000x reference)
//
#include <hip/hip_runtime.h>
#include <hip/hip_bf16.h>

typedef short short8 __attribute__((ext_vector_type(8)));
typedef float f32x16 __attribute__((ext_vector_type(16)));

#define MFMA32 __builtin_amdgcn_mfma_f32_32x32x16_bf16
#define HWPX 65536

#define GLDS16(gp, lp) __builtin_amdgcn_global_load_lds( \
    (const __attribute__((address_space(1))) unsigned int*)(gp), \
    (__attribute__((address_space(3))) unsigned int*)(lp), 16, 0, 0)

__device__ __forceinline__ unsigned short f2bf(float f) {
  unsigned u = __float_as_uint(f);
  u += 0x7FFF + ((u >> 16) & 1);
  return (unsigned short)(u >> 16);
}
__device__ __forceinline__ float bf2f(unsigned short b) {
  return __uint_as_float(((unsigned)b) << 16);
}

// ---------------------------------------------------------------- MLP
__global__ void mlp_kernel(const float* __restrict__ pred_box,
                           const float* __restrict__ score,
                           const float* __restrict__ W1, const float* __restrict__ b1,
                           const float* __restrict__ W2, const float* __restrict__ b2,
                           const float* __restrict__ W3, const float* __restrict__ b3,
                           float* __restrict__ objf) {
  __shared__ float obj[25];
  __shared__ float h1[256];
  __shared__ float h2[256];
  const int box = blockIdx.x;
  const int tid = threadIdx.x;
  if (tid < 24) obj[tid] = pred_box[box * 24 + tid];
  if (tid == 24) obj[24] = score[box];
  __syncthreads();
  float acc = b1[tid];
  #pragma unroll
  for (int k = 0; k < 25; ++k) acc = fmaf(obj[k], W1[k * 256 + tid], acc);
  h1[tid] = fmaxf(acc, 0.f);
  __syncthreads();
  acc = b2[tid];
  #pragma unroll 8
  for (int k = 0; k < 256; ++k) acc = fmaf(h1[k], W2[k * 256 + tid], acc);
  h2[tid] = fmaxf(acc, 0.f);
  __syncthreads();
  acc = b3[tid];
  #pragma unroll 8
  for (int k = 0; k < 256; ++k) acc = fmaf(h2[k], W3[k * 256 + tid], acc);
  objf[box * 256 + tid] = acc * score[box];
}

// ---------------------------------------------------------------- box bounds
__global__ void bounds_kernel(const float* __restrict__ pred_box,
                              int* __restrict__ bnds) {
  const int t = threadIdx.x;
  const float* p = pred_box + t * 24;
  float gx0 = 1e30f, gx1 = -1e30f, gy0 = 1e30f, gy1 = -1e30f;
  #pragma unroll
  for (int j = 0; j < 8; ++j) {
    float gx = floorf((p[j * 3 + 0] + 51.2f) / 0.4f);
    float gy = floorf((p[j * 3 + 1] + 51.2f) / 0.4f);
    gx0 = fminf(gx0, gx); gx1 = fmaxf(gx1, gx);
    gy0 = fminf(gy0, gy); gy1 = fmaxf(gy1, gy);
  }
  bnds[t * 4 + 0] = (int)fminf(fmaxf(gx0, 0.f), 255.f);
  bnds[t * 4 + 1] = (int)fminf(fmaxf(gx1, 0.f), 255.f);
  bnds[t * 4 + 2] = (int)fminf(fmaxf(gy0, 0.f), 255.f);
  bnds[t * 4 + 3] = (int)fminf(fmaxf(gy1, 0.f), 255.f);
}

// ---------------------------------------------------------------- weight transform
// wt2 layout: [cv][tap][kslice(16)][coblk(8)][lane(64)][8ci] bf16 — each MFMA
// B-fragment (tap, 16-K slice, 32-co block) is one contiguous 1KB wave load.
__global__ void wt_kernel(const float* __restrict__ w, unsigned short* __restrict__ wt) {
  int i = blockIdx.x * 256 + threadIdx.x;          // 6*9*16*8*512 = 3,538,944
  int j = i & 7;
  int l = (i >> 3) & 63;
  int nb = (i >> 9) & 7;
  int ks = (i >> 12) & 15;
  int t2 = i >> 16;
  int tap = t2 % 9;
  int cv = t2 / 9;
  int co = nb * 32 + (l & 31);
  int ci = ks * 16 + ((l >> 5) << 3) + j;
  wt[i] = f2bf(w[(size_t)((cv * 256 + co) * 256 + ci) * 9 + tap]);
}

// ---------------------------------------------------------------- raster -> NHWC bf16
__global__ void raster_nhwc(const int* __restrict__ bnds,
                            const float* __restrict__ objf,
                            unsigned short* __restrict__ xB) {
  const int y = blockIdx.x;
  const int b = blockIdx.y;
  const int x = threadIdx.x;
  __shared__ int sb[128];
  __shared__ int lastA[256];
  if (x < 128) sb[x] = bnds[b * 128 + x];
  __syncthreads();
  int last = -1;
  #pragma unroll
  for (int n = 0; n < 32; ++n) {
    int bx0 = sb[n * 4 + 0], bx1 = sb[n * 4 + 1];
    int by0 = sb[n * 4 + 2], by1 = sb[n * 4 + 3];
    if (x >= bx0 && x <= bx1 && y >= by0 && y <= by1) last = n;
  }
  lastA[x] = last;
  __syncthreads();
  unsigned short* row = xB + ((size_t)b * HWPX + y * 256) * 256;
  for (int it = 0; it < 32; ++it) {
    int s = x + 256 * it;
    int px = s >> 5;
    int c8 = (s & 31) * 8;
    int ln = lastA[px];
    short8 v = {0, 0, 0, 0, 0, 0, 0, 0};
    if (ln >= 0) {
      const float* f = objf + (b * 32 + ln) * 256 + c8;
      #pragma unroll
      for (int j = 0; j < 8; ++j) v[j] = (short)f2bf(f[j]);
    }
    *(short8*)(row + px * 256 + c8) = v;
  }
}

// ---------------------------------------------------------------- implicit-GEMM conv 3x3, bf16 MFMA 32x32x16
// grid 2048 (4 batches x 512 tiles), XCD-swizzled. Block tile = 2 rows x 64 px x 256 co.
// 4 waves = 4 co-quarters; wave = 128 px x 64 co, acc[4][2] f32x16.
// Round-8 schedule: 3-buffer rotation, ONE barrier per chunk, stage 2 chunks
// ahead (provably retired via counted vmcnt), B ring depth 3 with cross-chunk
// roll (Bf[4], parity-static indices). No sched_barrier pins.
__global__ __launch_bounds__(256, 2) void conv_mfma(const unsigned short* __restrict__ in,
                                                    const unsigned short* __restrict__ wt,
                                                    const unsigned short* __restrict__ zbuf,
                                                    unsigned short* __restrict__ T,
                                                    float* __restrict__ part) {
  __shared__ unsigned short lds[3][16 * 528];
  const int bid0 = blockIdx.x;
  const int swz = (bid0 & 7) * 256 + (bid0 >> 3);    // 2048 = 8*256, bijective
  const int b = swz >> 9;
  const int bid = swz & 511;
  const int x0 = (bid & 3) * 64;
  const int y0 = (bid >> 2) * 2;
  const int tid = threadIdx.x;
  const int lane = tid & 63;
  const int wid = tid >> 6;                            // co-quarter
  const int h = lane >> 5;
  const int l31 = lane & 31;
  const int col0 = l31 * 8;

  const unsigned short* inb = in + (size_t)b * (HWPX * 256);
  unsigned short* Tb = T + (size_t)b * (HWPX * 256);

  f32x16 acc[4][2];
  #pragma unroll
  for (int a = 0; a < 4; ++a)
    #pragma unroll
    for (int n = 0; n < 2; ++n)
      #pragma unroll
      for (int r = 0; r < 16; ++r) acc[a][n][r] = 0.f;

  short8 Af[2][4];
  short8 Bf[4][2];
  short8 edgev;

  const unsigned short* wbase = wt + (size_t)(wid * 2) * 512 + lane * 8;

  auto stage4 = [&](int cc, int buf) {
    const int ci0 = cc * 32;
    #pragma unroll
    for (int i = 0; i < 4; ++i) {
      const int rowg = wid * 4 + i;
      const int row = rowg >> 2;
      const int g = rowg & 3;
      const int yg = y0 + row - 1;
      unsigned short* lp = &lds[buf][((row << 2) | ((g & 1) << 1) | (g >> 1)) * 528 + 8];
      const unsigned short* gp = ((unsigned)yg < 256u)
          ? inb + ((size_t)(yg * 256 + x0 + lane) * 256 + ci0 + g * 8)
          : zbuf + lane * 8;
      GLDS16(gp, lp);
    }
  };

  auto edge_load = [&](int cc) {
    edgev = (short8){0, 0, 0, 0, 0, 0, 0, 0};
    if (tid < 32) {
      int row = tid >> 3, side = (tid >> 2) & 1, g = tid & 3;
      int yg = y0 + row - 1;
      int xg = x0 + (side ? 64 : -1);
      if ((unsigned)yg < 256u && (unsigned)xg < 256u)
        edgev = *(const short8*)(inb + ((size_t)(yg * 256 + xg) * 256 + cc * 32 + g * 8));
    }
  };
  auto edge_store = [&](int buf) {
    if (tid < 32) {
      int row = tid >> 3, side = (tid >> 2) & 1, g = tid & 3;
      *(short8*)&lds[buf][((row << 2) | ((g & 1) << 1) | (g >> 1)) * 528 + (side ? 65 : 0) * 8] = edgev;
    }
  };

  #define LOADA(s, d) { \
    const int ks_ = (s) / 9, tap_ = (s) % 9, ky_ = tap_ / 3, kx_ = tap_ % 3; \
    const unsigned short* p_ = lbase + ky_ * 2112 + ks_ * 528 + kx_ * 8 + col0; \
    d[0] = *(const short8*)(p_); \
    d[1] = *(const short8*)(p_ + 256); \
    d[2] = *(const short8*)(p_ + 2112); \
    d[3] = *(const short8*)(p_ + 2368); }

  #define LOADBT(ccv, s, dst) { \
    const unsigned short* p_ = wbase + (size_t)((((s) % 9) * 16 + (ccv) * 2 + (s) / 9) * 8) * 512; \
    dst[0] = *(const short8*)(p_); dst[1] = *(const short8*)(p_ + 512); }

  // Step loop: global step t = 18c + s; ring slot (2c+s)%4 — parity-static.
  #define STEPLOOP(P) \
    _Pragma("unroll") \
    for (int s = 0; s < 18; ++s) { \
      if (s < 15) { LOADBT(c, s + 3, Bf[(2 * (P) + s + 3) % 4]); } \
      else if (c + 1 < 8) { LOADBT(c + 1, s - 15, Bf[(2 * (P) + s + 3) % 4]); } \
      if (s + 1 < 18) LOADA(s + 1, Af[(s + 1) & 1]); \
      __builtin_amdgcn_s_setprio(1); \
      _Pragma("unroll") \
      for (int mf = 0; mf < 4; ++mf) { \
        _Pragma("unroll") \
        for (int nf = 0; nf < 2; ++nf) \
          acc[mf][nf] = MFMA32(Af[s & 1][mf], Bf[(2 * (P) + s) % 4][nf], acc[mf][nf], 0, 0, 0); \
      } \
      __builtin_amdgcn_s_setprio(0); \
    }

  // ---- prologue. VMEM issue order: E0(1), S0(4), S1(4), B(6) = 15.
  // vmcnt(10) => E0+S0 retired (in-order); S1+B may fly.
  edge_load(0);
  stage4(0, 0);
  stage4(1, 1);
  LOADBT(0, 0, Bf[0]);
  LOADBT(0, 1, Bf[1]);
  LOADBT(0, 2, Bf[2]);
  edge_store(0);                                   // compiler waits E0
  asm volatile("s_waitcnt lgkmcnt(0)" ::: "memory");
  asm volatile("s_waitcnt vmcnt(10)" ::: "memory");
  __builtin_amdgcn_s_barrier();

  for (int c = 0; c < 8; ++c) {
    if (c + 2 < 8) stage4(c + 2, (c + 2) % 3);     // 2 chunks ahead
    if (c + 1 < 8) edge_load(c + 1);               // hides under compute
    const unsigned short* lbase = &lds[c % 3][0] + h * 1056;
    LOADA(0, Af[0]);
    if (c & 1) { STEPLOOP(1) } else { STEPLOOP(0) }
    if (c + 1 < 8) edge_store((c + 1) % 3);        // disjoint from stage target
    if (c < 7) {
      asm volatile("s_waitcnt lgkmcnt(0)" ::: "memory");
      // end-of-iter outstanding: stage(c+2)(4) + rollB(6) = 10 -> stage(c+1)
      // (older) provably retired. c==6: no stage(8), only rollB(6).
      if (c == 6) { asm volatile("s_waitcnt vmcnt(6)" ::: "memory"); }
      else        { asm volatile("s_waitcnt vmcnt(10)" ::: "memory"); }
      __builtin_amdgcn_s_barrier();
    }
  }

  // epilogue: bf16 NHWC store + fp32 BN partial sums
  #pragma unroll
  for (int mf = 0; mf < 4; ++mf)
    #pragma unroll
    for (int nf = 0; nf < 2; ++nf) {
      unsigned short* o = Tb + ((size_t)((y0 + (mf >> 1)) * 256) + x0 + (mf & 1) * 32) * 256
                          + wid * 64 + nf * 32 + l31;
      #pragma unroll
      for (int r = 0; r < 16; ++r) {
        int m = (r & 3) + 8 * (r >> 2) + 4 * h;
        o[(size_t)m * 256] = f2bf(acc[mf][nf][r]);
      }
    }
  #pragma unroll
  for (int nf = 0; nf < 2; ++nf) {
    float s = 0.f, s2 = 0.f;
    #pragma unroll
    for (int mf = 0; mf < 4; ++mf)
      #pragma unroll
      for (int r = 0; r < 16; ++r) {
        float v = acc[mf][nf][r];
        s += v; s2 += v * v;
      }
    s += __shfl_xor(s, 32);
    s2 += __shfl_xor(s2, 32);
    if (lane < 32) {
      part[((size_t)swz * 256 + wid * 64 + nf * 32 + lane) * 2] = s;
      part[((size_t)swz * 256 + wid * 64 + nf * 32 + lane) * 2 + 1] = s2;
    }
  }
  #undef LOADA
  #undef LOADBT
  #undef STEPLOOP
}

// ---------------------------------------------------------------- BN stats reduce, grid (256 ch, 4 b)
__global__ void stats2(const float* __restrict__ part,
                       const float* __restrict__ g, const float* __restrict__ be,
                       float* __restrict__ sc, float* __restrict__ sh) {
  const int ch = blockIdx.x;
  const int b = blockIdx.y;
  const int t = threadIdx.x;
  double s = 0.0, s2 = 0.0;
  #pragma unroll
  for (int i = 0; i < 2; ++i) {
    int p = b * 512 + t + i * 256;
    s += (double)part[((size_t)p * 256 + ch) * 2];
    s2 += (double)part[((size_t)p * 256 + ch) * 2 + 1];
  }
  #pragma unroll
  for (int off = 32; off > 0; off >>= 1) {
    s += __shfl_down(s, off);
    s2 += __shfl_down(s2, off);
  }
  __shared__ double ls[4], ls2[4];
  if ((t & 63) == 0) { ls[t >> 6] = s; ls2[t >> 6] = s2; }
  __syncthreads();
  if (t == 0) {
    double S = ls[0] + ls[1] + ls[2] + ls[3];
    double S2 = ls2[0] + ls2[1] + ls2[2] + ls2[3];
    double m = S / 65536.0;
    double var = S2 / 65536.0 - m * m;
    double inv = 1.0 / sqrt(var + 1e-5);
    float scv = (float)inv * g[ch];
    sc[b * 256 + ch] = scv;
    sh[b * 256 + ch] = be[ch] - (float)m * scv;
  }
}

// ---------------------------------------------------------------- BN+relu: bf16 T -> bf16 yB (all batches)
__global__ void bnrelu(const unsigned short* __restrict__ T,
                       const float* __restrict__ sc, const float* __restrict__ sh,
                       unsigned short* __restrict__ yB) {
  #pragma unroll
  for (int it = 0; it < 8; ++it) {
    size_t e = (size_t)it * 1048576 + blockIdx.x * 256 + threadIdx.x;  // short8 idx
    int b = (int)(e >> 21);
    int ch8 = (int)(e & 31);
    const float* scp = sc + b * 256 + ch8 * 8;
    const float* shp = sh + b * 256 + ch8 * 8;
    float4 s0 = ((const float4*)scp)[0], s1 = ((const float4*)scp)[1];
    float4 h0 = ((const float4*)shp)[0], h1 = ((const float4*)shp)[1];
    float scv[8] = {s0.x, s0.y, s0.z, s0.w, s1.x, s1.y, s1.z, s1.w};
    float shv[8] = {h0.x, h0.y, h0.z, h0.w, h1.x, h1.y, h1.z, h1.w};
    short8 v = ((const short8*)T)[e];
    short8 o;
    #pragma unroll
    for (int j = 0; j < 8; ++j)
      o[j] = (short)f2bf(fmaxf(fmaf(bf2f((unsigned short)v[j]), scv[j], shv[j]), 0.f));
    ((short8*)yB)[e] = o;
  }
}

// ---------------------------------------------------------------- BN + residual + relu -> xB bf16 (k<2)
__global__ void bnres(const unsigned short* __restrict__ T,
                      const float* __restrict__ sc, const float* __restrict__ sh,
                      unsigned short* __restrict__ xB) {
  #pragma unroll
  for (int it = 0; it < 8; ++it) {
    size_t e = (size_t)it * 1048576 + blockIdx.x * 256 + threadIdx.x;
    int b = (int)(e >> 21);
    int ch8 = (int)(e & 31);
    const float* scp = sc + b * 256 + ch8 * 8;
    const float* shp = sh + b * 256 + ch8 * 8;
    float4 s0 = ((const float4*)scp)[0], s1 = ((const float4*)scp)[1];
    float4 h0 = ((const float4*)shp)[0], h1 = ((const float4*)shp)[1];
    float scv[8] = {s0.x, s0.y, s0.z, s0.w, s1.x, s1.y, s1.z, s1.w};
    float shv[8] = {h0.x, h0.y, h0.z, h0.w, h1.x, h1.y, h1.z, h1.w};
    short8 v = ((const short8*)T)[e];
    short8 rb = ((const short8*)xB)[e];
    short8 o;
    #pragma unroll
    for (int j = 0; j < 8; ++j) {
      float f = fmaf(bf2f((unsigned short)v[j]), scv[j], shv[j]) + bf2f((unsigned short)rb[j]);
      o[j] = (short)f2bf(fmaxf(f, 0.f));
    }
    ((short8*)xB)[e] = o;
  }
}

// ---------------------------------------------------------------- final: BN + residual + relu + NHWC->NCHW fp32
// grid (4096, 4): bx -> pxb (64px), chb (64ch); by = batch.
__global__ void bnres_tr(const unsigned short* __restrict__ T,
                         const float* __restrict__ sc, const float* __restrict__ sh,
                         const unsigned short* __restrict__ xB,
                         float* __restrict__ out) {
  __shared__ float tl[64][65];
  const int pxb = blockIdx.x >> 2;
  const int chb = blockIdx.x & 3;
  const int b = blockIdx.y;
  const int px0 = pxb * 64;
  const int ch0 = chb * 64;
  const int tid = threadIdx.x;
  #pragma unroll
  for (int i = 0; i < 2; ++i) {
    int p = (tid >> 3) + 32 * i;
    int c8 = (tid & 7) * 8;
    size_t e = ((size_t)b * HWPX + px0 + p) * 256 + ch0 + c8;
    const float* scp = sc + b * 256 + ch0 + c8;
    const float* shp = sh + b * 256 + ch0 + c8;
    float4 s0 = ((const float4*)scp)[0], s1 = ((const float4*)scp)[1];
    float4 h0 = ((const float4*)shp)[0], h1 = ((const float4*)shp)[1];
    float scv[8] = {s0.x, s0.y, s0.z, s0.w, s1.x, s1.y, s1.z, s1.w};
    float shv[8] = {h0.x, h0.y, h0.z, h0.w, h1.x, h1.y, h1.z, h1.w};
    short8 v = *(const short8*)(T + e);
    short8 rb = *(const short8*)(xB + e);
    #pragma unroll
    for (int j = 0; j < 8; ++j) {
      float f = fmaf(bf2f((unsigned short)v[j]), scv[j], shv[j]) + bf2f((unsigned short)rb[j]);
      tl[p][c8 + j] = fmaxf(f, 0.f);
    }
  }
  __syncthreads();
  float* ob = out + (size_t)b * (HWPX * 256);
  #pragma unroll
  for (int i = 0; i < 16; ++i) {
    int c = (tid >> 6) + 4 * i;
    int p = tid & 63;
    ob[(size_t)(ch0 + c) * HWPX + px0 + p] = tl[p][c];
  }
}

// ----------------------------------------------------------------
extern "C" void kernel_launch(void* const* d_in, const int* in_sizes, int n_in,
                              void* d_out, int out_size, void* d_ws, size_t ws_size,
                              hipStream_t stream) {
  const float* pred_box   = (const float*)d_in[0];
  const float* pred_score = (const float*)d_in[1];
  const float* W1 = (const float*)d_in[2];
  const float* b1 = (const float*)d_in[3];
  const float* W2 = (const float*)d_in[4];
  const float* b2 = (const float*)d_in[5];
  const float* W3 = (const float*)d_in[6];
  const float* b3 = (const float*)d_in[7];
  const float* conv_w = (const float*)d_in[8];
  const float* gamma  = (const float*)d_in[9];
  const float* beta   = (const float*)d_in[10];
  float* out = (float*)d_out;

  char* wsb = (char*)d_ws;
  float* objf = (float*)(wsb + 0);                                      // 128 KB
  int*   bnds = (int*)(wsb + 0x40000);
  float* sc   = (float*)(wsb + 0x42000);                                // 4 KB
  float* sh   = (float*)(wsb + 0x44000);                                // 4 KB
  float* part = (float*)(wsb + 0x100000);                               // 4 MB
  unsigned short* zbuf = (unsigned short*)(wsb + 0x500000);             // 4 KB zeros
  unsigned short* wtAll = (unsigned short*)(wsb + 0x600000);            // 6.75 MB
  unsigned short* xB = (unsigned short*)(wsb + (size_t)16 * 1024 * 1024);   // 134 MB
  unsigned short* yB = (unsigned short*)(wsb + (size_t)160 * 1024 * 1024);  // 134 MB
  unsigned short* T  = (unsigned short*)(wsb + (size_t)304 * 1024 * 1024);  // 134 MB

  hipMemsetAsync(zbuf, 0, 4096, stream);
  mlp_kernel<<<128, 256, 0, stream>>>(pred_box, pred_score, W1, b1, W2, b2, W3, b3, objf);
  bounds_kernel<<<1, 128, 0, stream>>>(pred_box, bnds);
  wt_kernel<<<13824, 256, 0, stream>>>(conv_w, wtAll);
  raster_nhwc<<<dim3(256, 4), 256, 0, stream>>>(bnds, objf, xB);

  for (int k = 0; k < 3; ++k) {
    const unsigned short* wk0 = wtAll + (size_t)(k * 2 + 0) * 589824;
    const unsigned short* wk1 = wtAll + (size_t)(k * 2 + 1) * 589824;
    conv_mfma<<<2048, 256, 0, stream>>>(xB, wk0, zbuf, T, part);
    stats2<<<dim3(256, 4), 256, 0, stream>>>(part, gamma + (k * 2 + 0) * 256,
                                             beta + (k * 2 + 0) * 256, sc, sh);
    bnrelu<<<4096, 256, 0, stream>>>(T, sc, sh, yB);
    conv_mfma<<<2048, 256, 0, stream>>>(yB, wk1, zbuf, T, part);
    stats2<<<dim3(256, 4), 256, 0, stream>>>(part, gamma + (k * 2 + 1) * 256,
                                             beta + (k * 2 + 1) * 256, sc, sh);
    if (k < 2)
      bnres<<<4096, 256, 0, stream>>>(T, sc, sh, xB);
    else
      bnres_tr<<<dim3(4096, 4), 256, 0, stream>>>(T, sc, sh, xB, out);
  }
}

// Round 9
// 1961.736 us; speedup vs baseline: 4.1247x; 4.1247x over previous
//
#include <hip/hip_runtime.h>
#include <hip/hip_bf16.h>

typedef short short8 __attribute__((ext_vector_type(8)));
typedef float f32x16 __attribute__((ext_vector_type(16)));

#define MFMA32 __builtin_amdgcn_mfma_f32_32x32x16_bf16
#define HWPX 65536

#define GLDS16(gp, lp) __builtin_amdgcn_global_load_lds( \
    (const __attribute__((address_space(1))) unsigned int*)(gp), \
    (__attribute__((address_space(3))) unsigned int*)(lp), 16, 0, 0)

__device__ __forceinline__ unsigned short f2bf(float f) {
  unsigned u = __float_as_uint(f);
  u += 0x7FFF + ((u >> 16) & 1);
  return (unsigned short)(u >> 16);
}
__device__ __forceinline__ float bf2f(unsigned short b) {
  return __uint_as_float(((unsigned)b) << 16);
}

// ---------------------------------------------------------------- MLP
__global__ void mlp_kernel(const float* __restrict__ pred_box,
                           const float* __restrict__ score,
                           const float* __restrict__ W1, const float* __restrict__ b1,
                           const float* __restrict__ W2, const float* __restrict__ b2,
                           const float* __restrict__ W3, const float* __restrict__ b3,
                           float* __restrict__ objf) {
  __shared__ float obj[25];
  __shared__ float h1[256];
  __shared__ float h2[256];
  const int box = blockIdx.x;
  const int tid = threadIdx.x;
  if (tid < 24) obj[tid] = pred_box[box * 24 + tid];
  if (tid == 24) obj[24] = score[box];
  __syncthreads();
  float acc = b1[tid];
  #pragma unroll
  for (int k = 0; k < 25; ++k) acc = fmaf(obj[k], W1[k * 256 + tid], acc);
  h1[tid] = fmaxf(acc, 0.f);
  __syncthreads();
  acc = b2[tid];
  #pragma unroll 8
  for (int k = 0; k < 256; ++k) acc = fmaf(h1[k], W2[k * 256 + tid], acc);
  h2[tid] = fmaxf(acc, 0.f);
  __syncthreads();
  acc = b3[tid];
  #pragma unroll 8
  for (int k = 0; k < 256; ++k) acc = fmaf(h2[k], W3[k * 256 + tid], acc);
  objf[box * 256 + tid] = acc * score[box];
}

// ---------------------------------------------------------------- box bounds
__global__ void bounds_kernel(const float* __restrict__ pred_box,
                              int* __restrict__ bnds) {
  const int t = threadIdx.x;
  const float* p = pred_box + t * 24;
  float gx0 = 1e30f, gx1 = -1e30f, gy0 = 1e30f, gy1 = -1e30f;
  #pragma unroll
  for (int j = 0; j < 8; ++j) {
    float gx = floorf((p[j * 3 + 0] + 51.2f) / 0.4f);
    float gy = floorf((p[j * 3 + 1] + 51.2f) / 0.4f);
    gx0 = fminf(gx0, gx); gx1 = fmaxf(gx1, gx);
    gy0 = fminf(gy0, gy); gy1 = fmaxf(gy1, gy);
  }
  bnds[t * 4 + 0] = (int)fminf(fmaxf(gx0, 0.f), 255.f);
  bnds[t * 4 + 1] = (int)fminf(fmaxf(gx1, 0.f), 255.f);
  bnds[t * 4 + 2] = (int)fminf(fmaxf(gy0, 0.f), 255.f);
  bnds[t * 4 + 3] = (int)fminf(fmaxf(gy1, 0.f), 255.f);
}

// ---------------------------------------------------------------- weight transform
// wt2 layout: [cv][tap][kslice(16)][coblk(8)][lane(64)][8ci] bf16 — each MFMA
// B-fragment (tap, 16-K slice, 32-co block) is one contiguous 1KB wave load.
__global__ void wt_kernel(const float* __restrict__ w, unsigned short* __restrict__ wt) {
  int i = blockIdx.x * 256 + threadIdx.x;          // 6*9*16*8*512 = 3,538,944
  int j = i & 7;
  int l = (i >> 3) & 63;
  int nb = (i >> 9) & 7;
  int ks = (i >> 12) & 15;
  int t2 = i >> 16;
  int tap = t2 % 9;
  int cv = t2 / 9;
  int co = nb * 32 + (l & 31);
  int ci = ks * 16 + ((l >> 5) << 3) + j;
  wt[i] = f2bf(w[(size_t)((cv * 256 + co) * 256 + ci) * 9 + tap]);
}

// ---------------------------------------------------------------- raster -> NHWC bf16
__global__ void raster_nhwc(const int* __restrict__ bnds,
                            const float* __restrict__ objf,
                            unsigned short* __restrict__ xB) {
  const int y = blockIdx.x;
  const int b = blockIdx.y;
  const int x = threadIdx.x;
  __shared__ int sb[128];
  __shared__ int lastA[256];
  if (x < 128) sb[x] = bnds[b * 128 + x];
  __syncthreads();
  int last = -1;
  #pragma unroll
  for (int n = 0; n < 32; ++n) {
    int bx0 = sb[n * 4 + 0], bx1 = sb[n * 4 + 1];
    int by0 = sb[n * 4 + 2], by1 = sb[n * 4 + 3];
    if (x >= bx0 && x <= bx1 && y >= by0 && y <= by1) last = n;
  }
  lastA[x] = last;
  __syncthreads();
  unsigned short* row = xB + ((size_t)b * HWPX + y * 256) * 256;
  for (int it = 0; it < 32; ++it) {
    int s = x + 256 * it;
    int px = s >> 5;
    int c8 = (s & 31) * 8;
    int ln = lastA[px];
    short8 v = {0, 0, 0, 0, 0, 0, 0, 0};
    if (ln >= 0) {
      const float* f = objf + (b * 32 + ln) * 256 + c8;
      #pragma unroll
      for (int j = 0; j < 8; ++j) v[j] = (short)f2bf(f[j]);
    }
    *(short8*)(row + px * 256 + c8) = v;
  }
}

// ---------------------------------------------------------------- implicit-GEMM conv 3x3, bf16 MFMA 32x32x16
// grid 2048 (4 batches x 512 tiles), XCD-swizzled. Block tile = 2 rows x 64 px x 256 co.
// 4 waves = 4 co-quarters; wave = 128 px x 64 co, acc[4][2] f32x16.
// Round-9 = Round-6 schedule (best measured) with the wait corrected to
// vmcnt(4): queue at that point = stage(c+1)(4, just issued) [+ stage(c) if
// unretired]; vmcnt(4) PROVES stage(c) landed before barrier #1 while keeping
// stage(c+1) in flight. All other loads are compiler-waited before use.
__global__ __launch_bounds__(256, 2) void conv_mfma(const unsigned short* __restrict__ in,
                                                    const unsigned short* __restrict__ wt,
                                                    const unsigned short* __restrict__ zbuf,
                                                    unsigned short* __restrict__ T,
                                                    float* __restrict__ part) {
  __shared__ unsigned short lds[2][16 * 528];
  const int bid0 = blockIdx.x;
  const int swz = (bid0 & 7) * 256 + (bid0 >> 3);    // 2048 = 8*256, bijective
  const int b = swz >> 9;
  const int bid = swz & 511;
  const int x0 = (bid & 3) * 64;
  const int y0 = (bid >> 2) * 2;
  const int tid = threadIdx.x;
  const int lane = tid & 63;
  const int wid = tid >> 6;                            // co-quarter
  const int h = lane >> 5;
  const int l31 = lane & 31;
  const int col0 = l31 * 8;

  const unsigned short* inb = in + (size_t)b * (HWPX * 256);
  unsigned short* Tb = T + (size_t)b * (HWPX * 256);

  f32x16 acc[4][2];
  #pragma unroll
  for (int a = 0; a < 4; ++a)
    #pragma unroll
    for (int n = 0; n < 2; ++n)
      #pragma unroll
      for (int r = 0; r < 16; ++r) acc[a][n][r] = 0.f;

  const unsigned short* wbase = wt + (size_t)(wid * 2) * 512 + lane * 8;

  short8 edgev;

  auto stage = [&](int c1, int buf) {
    const int ci0 = c1 * 32;
    #pragma unroll
    for (int i = 0; i < 4; ++i) {
      const int rowg = wid * 4 + i;
      const int row = rowg >> 2;
      const int g = rowg & 3;
      const int yg = y0 + row - 1;
      unsigned short* lp = &lds[buf][((row << 2) | ((g & 1) << 1) | (g >> 1)) * 528 + 8];
      const unsigned short* gp;
      if ((unsigned)yg < 256u)
        gp = inb + ((size_t)(yg * 256 + x0 + lane) * 256 + ci0 + g * 8);
      else
        gp = zbuf + lane * 8;
      GLDS16(gp, lp);
    }
  };

  auto edge_load = [&](int c1) {
    edgev = (short8){0, 0, 0, 0, 0, 0, 0, 0};
    if (tid < 32) {
      int row = tid >> 3, side = (tid >> 2) & 1, g = tid & 3;
      int yg = y0 + row - 1;
      int xg = x0 + (side ? 64 : -1);
      if ((unsigned)yg < 256u && (unsigned)xg < 256u)
        edgev = *(const short8*)(inb + ((size_t)(yg * 256 + xg) * 256 + c1 * 32 + g * 8));
    }
  };
  auto edge_store = [&](int buf) {
    if (tid < 32) {
      int row = tid >> 3, side = (tid >> 2) & 1, g = tid & 3;
      *(short8*)&lds[buf][((row << 2) | ((g & 1) << 1) | (g >> 1)) * 528 + (side ? 65 : 0) * 8] = edgev;
    }
  };

  #define LOADA(s, d) { \
    const int ks_ = (s) / 9, tap_ = (s) % 9, ky_ = tap_ / 3, kx_ = tap_ % 3; \
    const unsigned short* p_ = lbase + ky_ * 2112 + ks_ * 528 + kx_ * 8 + col0; \
    d[0] = *(const short8*)(p_); \
    d[1] = *(const short8*)(p_ + 256); \
    d[2] = *(const short8*)(p_ + 2112); \
    d[3] = *(const short8*)(p_ + 2368); }

  #define LOADB(s, d) { \
    const unsigned short* p_ = wbase + (size_t)((((s) % 9) * 16 + c * 2 + (s) / 9) * 8) * 512; \
    d[0] = *(const short8*)(p_); d[1] = *(const short8*)(p_ + 512); }

  auto compute = [&](int buf, int c) {
    const unsigned short* lbase = &lds[buf][0] + h * 1056;
    short8 Af[2][4];
    short8 Bf[3][2];
    LOADA(0, Af[0]);
    LOADB(0, Bf[0]);
    LOADB(1, Bf[1]);
    #pragma unroll
    for (int s = 0; s < 18; ++s) {
      if (s + 2 < 18) LOADB(s + 2, Bf[(s + 2) % 3]);
      if (s + 1 < 18) LOADA(s + 1, Af[(s + 1) & 1]);
      __builtin_amdgcn_s_setprio(1);
      #pragma unroll
      for (int mf = 0; mf < 4; ++mf)
        #pragma unroll
        for (int nf = 0; nf < 2; ++nf)
          acc[mf][nf] = MFMA32(Af[s & 1][mf], Bf[s % 3][nf], acc[mf][nf], 0, 0, 0);
      __builtin_amdgcn_s_setprio(0);
    }
  };

  // prologue: stage chunk 0, fill its edges; edge ds_write drained before first barrier
  stage(0, 0);
  edge_load(0);
  edge_store(0);
  asm volatile("s_waitcnt lgkmcnt(0)" ::: "memory");

  int cur = 0;
  for (int c = 0; c < 8; ++c) {
    // (a) issue next-chunk stage into cur^1 — safe: barrier #2 of previous
    //     iteration guarantees all waves finished reading cur^1 (chunk c-1).
    if (c < 7) {
      stage(c + 1, cur ^ 1);
      // (b) queue = stage(c+1)(4) [+ stage(c) if unretired]; vmcnt(4) ensures
      //     stage(c) landed, keeps stage(c+1) in flight.
      asm volatile("s_waitcnt vmcnt(4)" ::: "memory");
    } else {
      asm volatile("s_waitcnt vmcnt(0)" ::: "memory");
    }
    // (c) barrier #1: every wave's stage(c) data is in LDS -> chunk c readable
    __builtin_amdgcn_s_barrier();
    if (c < 7) edge_load(c + 1);          // latency hides under compute
    compute(cur, c);
    if (c < 7) edge_store(cur ^ 1);       // disjoint from stage(c+1) slots
    // (e/f) edge ds_write drained, then barrier #2: all reads of cur done
    asm volatile("s_waitcnt lgkmcnt(0)" ::: "memory");
    __builtin_amdgcn_s_barrier();
    cur ^= 1;
  }

  // epilogue: bf16 NHWC store + fp32 BN partial sums
  #pragma unroll
  for (int mf = 0; mf < 4; ++mf)
    #pragma unroll
    for (int nf = 0; nf < 2; ++nf) {
      unsigned short* o = Tb + ((size_t)((y0 + (mf >> 1)) * 256) + x0 + (mf & 1) * 32) * 256
                          + wid * 64 + nf * 32 + l31;
      #pragma unroll
      for (int r = 0; r < 16; ++r) {
        int m = (r & 3) + 8 * (r >> 2) + 4 * h;
        o[(size_t)m * 256] = f2bf(acc[mf][nf][r]);
      }
    }
  #pragma unroll
  for (int nf = 0; nf < 2; ++nf) {
    float s = 0.f, s2 = 0.f;
    #pragma unroll
    for (int mf = 0; mf < 4; ++mf)
      #pragma unroll
      for (int r = 0; r < 16; ++r) {
        float v = acc[mf][nf][r];
        s += v; s2 += v * v;
      }
    s += __shfl_xor(s, 32);
    s2 += __shfl_xor(s2, 32);
    if (lane < 32) {
      part[((size_t)swz * 256 + wid * 64 + nf * 32 + lane) * 2] = s;
      part[((size_t)swz * 256 + wid * 64 + nf * 32 + lane) * 2 + 1] = s2;
    }
  }
  #undef LOADA
  #undef LOADB
}

// ---------------------------------------------------------------- BN stats reduce, grid (256 ch, 4 b)
__global__ void stats2(const float* __restrict__ part,
                       const float* __restrict__ g, const float* __restrict__ be,
                       float* __restrict__ sc, float* __restrict__ sh) {
  const int ch = blockIdx.x;
  const int b = blockIdx.y;
  const int t = threadIdx.x;
  double s = 0.0, s2 = 0.0;
  #pragma unroll
  for (int i = 0; i < 2; ++i) {
    int p = b * 512 + t + i * 256;
    s += (double)part[((size_t)p * 256 + ch) * 2];
    s2 += (double)part[((size_t)p * 256 + ch) * 2 + 1];
  }
  #pragma unroll
  for (int off = 32; off > 0; off >>= 1) {
    s += __shfl_down(s, off);
    s2 += __shfl_down(s2, off);
  }
  __shared__ double ls[4], ls2[4];
  if ((t & 63) == 0) { ls[t >> 6] = s; ls2[t >> 6] = s2; }
  __syncthreads();
  if (t == 0) {
    double S = ls[0] + ls[1] + ls[2] + ls[3];
    double S2 = ls2[0] + ls2[1] + ls2[2] + ls2[3];
    double m = S / 65536.0;
    double var = S2 / 65536.0 - m * m;
    double inv = 1.0 / sqrt(var + 1e-5);
    float scv = (float)inv * g[ch];
    sc[b * 256 + ch] = scv;
    sh[b * 256 + ch] = be[ch] - (float)m * scv;
  }
}

// ---------------------------------------------------------------- BN+relu: bf16 T -> bf16 yB (all batches)
__global__ void bnrelu(const unsigned short* __restrict__ T,
                       const float* __restrict__ sc, const float* __restrict__ sh,
                       unsigned short* __restrict__ yB) {
  #pragma unroll
  for (int it = 0; it < 8; ++it) {
    size_t e = (size_t)it * 1048576 + blockIdx.x * 256 + threadIdx.x;  // short8 idx
    int b = (int)(e >> 21);
    int ch8 = (int)(e & 31);
    const float* scp = sc + b * 256 + ch8 * 8;
    const float* shp = sh + b * 256 + ch8 * 8;
    float4 s0 = ((const float4*)scp)[0], s1 = ((const float4*)scp)[1];
    float4 h0 = ((const float4*)shp)[0], h1 = ((const float4*)shp)[1];
    float scv[8] = {s0.x, s0.y, s0.z, s0.w, s1.x, s1.y, s1.z, s1.w};
    float shv[8] = {h0.x, h0.y, h0.z, h0.w, h1.x, h1.y, h1.z, h1.w};
    short8 v = ((const short8*)T)[e];
    short8 o;
    #pragma unroll
    for (int j = 0; j < 8; ++j)
      o[j] = (short)f2bf(fmaxf(fmaf(bf2f((unsigned short)v[j]), scv[j], shv[j]), 0.f));
    ((short8*)yB)[e] = o;
  }
}

// ---------------------------------------------------------------- BN + residual + relu -> xB bf16 (k<2)
__global__ void bnres(const unsigned short* __restrict__ T,
                      const float* __restrict__ sc, const float* __restrict__ sh,
                      unsigned short* __restrict__ xB) {
  #pragma unroll
  for (int it = 0; it < 8; ++it) {
    size_t e = (size_t)it * 1048576 + blockIdx.x * 256 + threadIdx.x;
    int b = (int)(e >> 21);
    int ch8 = (int)(e & 31);
    const float* scp = sc + b * 256 + ch8 * 8;
    const float* shp = sh + b * 256 + ch8 * 8;
    float4 s0 = ((const float4*)scp)[0], s1 = ((const float4*)scp)[1];
    float4 h0 = ((const float4*)shp)[0], h1 = ((const float4*)shp)[1];
    float scv[8] = {s0.x, s0.y, s0.z, s0.w, s1.x, s1.y, s1.z, s1.w};
    float shv[8] = {h0.x, h0.y, h0.z, h0.w, h1.x, h1.y, h1.z, h1.w};
    short8 v = ((const short8*)T)[e];
    short8 rb = ((const short8*)xB)[e];
    short8 o;
    #pragma unroll
    for (int j = 0; j < 8; ++j) {
      float f = fmaf(bf2f((unsigned short)v[j]), scv[j], shv[j]) + bf2f((unsigned short)rb[j]);
      o[j] = (short)f2bf(fmaxf(f, 0.f));
    }
    ((short8*)xB)[e] = o;
  }
}

// ---------------------------------------------------------------- final: BN + residual + relu + NHWC->NCHW fp32
// grid (4096, 4): bx -> pxb (64px), chb (64ch); by = batch.
__global__ void bnres_tr(const unsigned short* __restrict__ T,
                         const float* __restrict__ sc, const float* __restrict__ sh,
                         const unsigned short* __restrict__ xB,
                         float* __restrict__ out) {
  __shared__ float tl[64][65];
  const int pxb = blockIdx.x >> 2;
  const int chb = blockIdx.x & 3;
  const int b = blockIdx.y;
  const int px0 = pxb * 64;
  const int ch0 = chb * 64;
  const int tid = threadIdx.x;
  #pragma unroll
  for (int i = 0; i < 2; ++i) {
    int p = (tid >> 3) + 32 * i;
    int c8 = (tid & 7) * 8;
    size_t e = ((size_t)b * HWPX + px0 + p) * 256 + ch0 + c8;
    const float* scp = sc + b * 256 + ch0 + c8;
    const float* shp = sh + b * 256 + ch0 + c8;
    float4 s0 = ((const float4*)scp)[0], s1 = ((const float4*)scp)[1];
    float4 h0 = ((const float4*)shp)[0], h1 = ((const float4*)shp)[1];
    float scv[8] = {s0.x, s0.y, s0.z, s0.w, s1.x, s1.y, s1.z, s1.w};
    float shv[8] = {h0.x, h0.y, h0.z, h0.w, h1.x, h1.y, h1.z, h1.w};
    short8 v = *(const short8*)(T + e);
    short8 rb = *(const short8*)(xB + e);
    #pragma unroll
    for (int j = 0; j < 8; ++j) {
      float f = fmaf(bf2f((unsigned short)v[j]), scv[j], shv[j]) + bf2f((unsigned short)rb[j]);
      tl[p][c8 + j] = fmaxf(f, 0.f);
    }
  }
  __syncthreads();
  float* ob = out + (size_t)b * (HWPX * 256);
  #pragma unroll
  for (int i = 0; i < 16; ++i) {
    int c = (tid >> 6) + 4 * i;
    int p = tid & 63;
    ob[(size_t)(ch0 + c) * HWPX + px0 + p] = tl[p][c];
  }
}

// ----------------------------------------------------------------
extern "C" void kernel_launch(void* const* d_in, const int* in_sizes, int n_in,
                              void* d_out, int out_size, void* d_ws, size_t ws_size,
                              hipStream_t stream) {
  const float* pred_box   = (const float*)d_in[0];
  const float* pred_score = (const float*)d_in[1];
  const float* W1 = (const float*)d_in[2];
  const float* b1 = (const float*)d_in[3];
  const float* W2 = (const float*)d_in[4];
  const float* b2 = (const float*)d_in[5];
  const float* W3 = (const float*)d_in[6];
  const float* b3 = (const float*)d_in[7];
  const float* conv_w = (const float*)d_in[8];
  const float* gamma  = (const float*)d_in[9];
  const float* beta   = (const float*)d_in[10];
  float* out = (float*)d_out;

  char* wsb = (char*)d_ws;
  float* objf = (float*)(wsb + 0);                                      // 128 KB
  int*   bnds = (int*)(wsb + 0x40000);
  float* sc   = (float*)(wsb + 0x42000);                                // 4 KB
  float* sh   = (float*)(wsb + 0x44000);                                // 4 KB
  float* part = (float*)(wsb + 0x100000);                               // 4 MB
  unsigned short* zbuf = (unsigned short*)(wsb + 0x500000);             // 4 KB zeros
  unsigned short* wtAll = (unsigned short*)(wsb + 0x600000);            // 6.75 MB
  unsigned short* xB = (unsigned short*)(wsb + (size_t)16 * 1024 * 1024);   // 134 MB
  unsigned short* yB = (unsigned short*)(wsb + (size_t)160 * 1024 * 1024);  // 134 MB
  unsigned short* T  = (unsigned short*)(wsb + (size_t)304 * 1024 * 1024);  // 134 MB

  hipMemsetAsync(zbuf, 0, 4096, stream);
  mlp_kernel<<<128, 256, 0, stream>>>(pred_box, pred_score, W1, b1, W2, b2, W3, b3, objf);
  bounds_kernel<<<1, 128, 0, stream>>>(pred_box, bnds);
  wt_kernel<<<13824, 256, 0, stream>>>(conv_w, wtAll);
  raster_nhwc<<<dim3(256, 4), 256, 0, stream>>>(bnds, objf, xB);

  for (int k = 0; k < 3; ++k) {
    const unsigned short* wk0 = wtAll + (size_t)(k * 2 + 0) * 589824;
    const unsigned short* wk1 = wtAll + (size_t)(k * 2 + 1) * 589824;
    conv_mfma<<<2048, 256, 0, stream>>>(xB, wk0, zbuf, T, part);
    stats2<<<dim3(256, 4), 256, 0, stream>>>(part, gamma + (k * 2 + 0) * 256,
                                             beta + (k * 2 + 0) * 256, sc, sh);
    bnrelu<<<4096, 256, 0, stream>>>(T, sc, sh, yB);
    conv_mfma<<<2048, 256, 0, stream>>>(yB, wk1, zbuf, T, part);
    stats2<<<dim3(256, 4), 256, 0, stream>>>(part, gamma + (k * 2 + 1) * 256,
                                             beta + (k * 2 + 1) * 256, sc, sh);
    if (k < 2)
      bnres<<<4096, 256, 0, stream>>>(T, sc, sh, xB);
    else
      bnres_tr<<<dim3(4096, 4), 256, 0, stream>>>(T, sc, sh, xB, out);
  }
}